// Round 7
// baseline (215.996 us; speedup 1.0000x reference)
//
#include <hip/hip_runtime.h>
#include <stdint.h>

typedef unsigned short u16;
typedef __attribute__((ext_vector_type(8))) __bf16 bf16x8;
typedef __attribute__((ext_vector_type(4))) float f32x4;

#define MAXMT 40
#define N_TOK 2048
#define DDIM 1024
#define FDIM 1024

#define DEV static __device__ __forceinline__

DEV float bf2f(u16 u) {
    union { uint32_t i; float f; } v;
    v.i = ((uint32_t)u) << 16;
    return v.f;
}
DEV u16 f2bf(float f) {
    union { float f; uint32_t i; } v;
    v.f = f;
    uint32_t x = v.i;
    return (u16)((x + 0x7fffu + ((x >> 16) & 1u)) >> 16);  // RNE
}

// async global->LDS, 16B per lane; lds base wave-uniform, HW writes lane i at base+16*i
DEV void async_copy16(const u16* gsrc, u16* ldst) {
    __builtin_amdgcn_global_load_lds(
        (const __attribute__((address_space(1))) void*)(uintptr_t)gsrc,
        (__attribute__((address_space(3))) void*)(uint32_t)(uintptr_t)ldst,
        16, 0, 0);
}

// per-block dtype sniff: sample first 256 u16; fp32-reinterpreted data ~36% wild exponents.
DEV int sniff_fp(const void* p, int tid, int* scnt) {
    if (tid == 0) *scnt = 0;
    __syncthreads();
    u16 u = ((const u16*)p)[tid & 255];
    int e = (u >> 7) & 0xff;
    if (e != 0 && (e < 90 || e > 160)) atomicAdd(scnt, 1);
    __syncthreads();
    return *scnt > 64;
}

// ===================== mega: 3x8 weight transposes (z<24) + gating/normx (z>=24) =====================
__global__ void k_mega(const void* __restrict__ x, const void* __restrict__ wg,
                       const void* __restrict__ w1, const void* __restrict__ w3,
                       const void* __restrict__ w2, u16* __restrict__ wt,
                       u16* __restrict__ xb, void* __restrict__ out_base,
                       int* __restrict__ te, float* __restrict__ tw) {
    __shared__ int scnt;
    __shared__ __align__(16) u16 s[64][72];
    int z = blockIdx.z, tid = threadIdx.x;

    if (z < 24) {
        // ---- transpose plane: which tensor = z/8, local mat = z%8 ----
        int which = z >> 3, mat = z & 7;
        const void* src0 = which == 0 ? w1 : (which == 1 ? w3 : w2);
        int fp = sniff_fp(src0, tid, &scnt);
        u16* dst = wt + ((size_t)z) * 1048576;
        int r = tid >> 2, seg = tid & 3;
        int r0 = blockIdx.y * 64, c0 = blockIdx.x * 64;
        size_t base = (size_t)mat * 1048576 + (size_t)(r0 + r) * 1024 + c0 + seg * 16;
        u16 v[16];
        if (fp) {
            const float* sp = (const float*)src0 + base;
#pragma unroll
            for (int q = 0; q < 4; q++) {
                float4 f = ((const float4*)sp)[q];
                v[q * 4 + 0] = f2bf(f.x); v[q * 4 + 1] = f2bf(f.y);
                v[q * 4 + 2] = f2bf(f.z); v[q * 4 + 3] = f2bf(f.w);
            }
        } else {
            const u16* sp = (const u16*)src0 + base;
            *(uint4*)&v[0] = *(const uint4*)sp;
            *(uint4*)&v[8] = *(const uint4*)(sp + 8);
        }
        *(uint4*)&s[r][seg * 16] = *(const uint4*)&v[0];
        *(uint4*)&s[r][seg * 16 + 8] = *(const uint4*)&v[8];
        __syncthreads();
        // conflict-free read mapping: col = lane, bank = (const + lane/2) % 32
        int col = tid & 63, rgrp = tid >> 6;
        u16 tmp[16];
#pragma unroll
        for (int j = 0; j < 16; j++) tmp[j] = s[rgrp * 16 + j][col];
        u16* dp = dst + (size_t)(c0 + col) * 1024 + r0 + rgrp * 16;
        *(uint4*)dp = *(const uint4*)&tmp[0];
        *(uint4*)(dp + 8) = *(const uint4*)&tmp[8];
    } else {
        // ---- gating plane: 512 blocks, 4 tokens each; also emits xb (bf16 x) ----
        int fp = sniff_fp(x, tid, &scnt);
        int gi = (z - 24) * 256 + blockIdx.y * 16 + blockIdx.x;
        int wave = tid >> 6, lane = tid & 63;
        int n = gi * 4 + wave;
        float acc[8];
#pragma unroll
        for (int e = 0; e < 8; e++) acc[e] = 0.f;
        if (fp) {
            const float* xp = (const float*)x + (size_t)n * DDIM;
            const float* wp = (const float*)wg;
            for (int it = 0; it < 16; ++it) {
                int d = it * 64 + lane;
                float xv = xp[d];
                xb[(size_t)n * DDIM + d] = f2bf(xv);
#pragma unroll
                for (int e = 0; e < 8; e++) acc[e] += xv * wp[e * DDIM + d];
            }
        } else {
            const u16* xp = (const u16*)x + (size_t)n * DDIM;
            const u16* wp = (const u16*)wg;
            for (int it = 0; it < 16; ++it) {
                int d = it * 64 + lane;
                u16 raw = xp[d];
                xb[(size_t)n * DDIM + d] = raw;
                float xv = bf2f(raw);
#pragma unroll
                for (int e = 0; e < 8; e++) acc[e] += xv * bf2f(wp[e * DDIM + d]);
            }
        }
#pragma unroll
        for (int e = 0; e < 8; e++) {
            for (int off = 32; off; off >>= 1) acc[e] += __shfl_xor(acc[e], off);
        }
        if (lane < 8) {
            if (fp) ((float*)out_base + (size_t)N_TOK * DDIM)[n * 8 + lane] = acc[lane];
            else    ((u16*)out_base + (size_t)N_TOK * DDIM)[n * 8 + lane] = f2bf(acc[lane]);
        }
        if (lane == 0) {
            int e0 = 0; float b0 = acc[0];
            for (int e = 1; e < 8; e++) if (acc[e] > b0) { b0 = acc[e]; e0 = e; }
            int e1 = -1; float b1 = -1e30f;
            for (int e = 0; e < 8; e++) if (e != e0 && acc[e] > b1) { b1 = acc[e]; e1 = e; }
            float m = fmaxf(b0, b1);
            float x0 = __expf(b0 - m), x1 = __expf(b1 - m);
            float sden = x0 + x1;
            te[n * 2] = e0; te[n * 2 + 1] = e1;
            tw[n * 2] = x0 / sden; tw[n * 2 + 1] = x1 / sden;
        }
    }
}

// ---------------- scheduling ----------------
__global__ void k_sched(const int* __restrict__ te, const float* __restrict__ tw,
                        int* __restrict__ pair_token, float* __restrict__ pair_weight,
                        int* __restrict__ sched) {
    __shared__ int cnt[8], cur[8];
    int t = threadIdx.x;
    if (t < 8) cnt[t] = 0;
    __syncthreads();
    for (int n = t; n < N_TOK; n += 256) {
        atomicAdd(&cnt[te[2 * n]], 1);
        atomicAdd(&cnt[te[2 * n + 1]], 1);
    }
    __syncthreads();
    if (t == 0) {
        int o = 0, mt = 0;
        for (int e = 0; e < 8; e++) {
            cur[e] = o;
            int c = cnt[e];
            for (int m0 = 0; m0 < c; m0 += 128) {
                sched[mt] = e;
                sched[MAXMT + mt] = o + m0;
                sched[2 * MAXMT + mt] = (c - m0 < 128) ? (c - m0) : 128;
                mt++;
            }
            o += c;
        }
        sched[3 * MAXMT] = mt;
        for (int i = mt; i < MAXMT; i++) { sched[i] = 0; sched[MAXMT + i] = 0; sched[2 * MAXMT + i] = 0; }
    }
    __syncthreads();
    for (int n = t; n < N_TOK; n += 256) {
#pragma unroll
        for (int s = 0; s < 2; s++) {
            int e = te[2 * n + s];
            int p = atomicAdd(&cur[e], 1);
            pair_token[p] = n;
            pair_weight[p] = tw[2 * n + s];
        }
    }
}

// ===================== fused SwiGLU GEMM: Abuf = silu(X@W1) * (X@W3) =====================
// Tile: 128 pairs x 64 f-cols, BK=64. LDS: sA 16K + sB1 8K + sB3 8K = 32 KB.
__launch_bounds__(256, 3)
__global__ void k_gemm13(const u16* __restrict__ xb, const u16* __restrict__ w1t,
                         const u16* __restrict__ w3t, const int* __restrict__ pair_token,
                         const int* __restrict__ sched, u16* __restrict__ Abuf) {
    __shared__ __align__(16) u16 smem[16384];     // 32 KB
    u16* sA  = smem;                              // 128x64
    u16* sB1 = smem + 8192;                       // 64x64
    u16* sB3 = smem + 12288;                      // 64x64

    int bn = blockIdx.x;          // 16 tiles of 64 cols
    int bm = blockIdx.y;
    int total = sched[3 * MAXMT];
    if (bm >= total) return;
    int e = sched[bm];
    int row0 = sched[MAXMT + bm];
    int rowsv = sched[2 * MAXMT + bm];

    int tid = threadIdx.x;
    int wave = tid >> 6, lane = tid & 63;
    int wm = wave & 1, wn = wave >> 1;            // wave: 64m x 32n
    int quad = lane >> 4, l15 = lane & 15;
    int lsub = lane >> 3, slot = lane & 7;

    const u16* gA[4]; u16* lA[4];
#pragma unroll
    for (int c = 0; c < 4; c++) {
        int row = c * 32 + wave * 8 + lsub;       // 0..127
        int cr = row < rowsv ? row : 0;
        int tok = pair_token[row0 + cr];
        int gch = slot ^ (row & 7);
        gA[c] = xb + (size_t)tok * DDIM + gch * 8;
        lA[c] = sA + c * 2048 + wave * 512;
    }
    const u16* gB1[2]; const u16* gB3[2]; int lBoff[2];
#pragma unroll
    for (int c = 0; c < 2; c++) {
        int row = c * 32 + wave * 8 + lsub;       // 0..63
        int gch = slot ^ (row & 7);
        int fcol = bn * 64 + row;
        gB1[c] = w1t + ((size_t)e * 1024 + fcol) * 1024 + gch * 8;
        gB3[c] = w3t + ((size_t)e * 1024 + fcol) * 1024 + gch * 8;
        lBoff[c] = c * 2048 + wave * 512;
    }

    f32x4 acc_h[4][2], acc_u[4][2];
#pragma unroll
    for (int i = 0; i < 4; i++)
#pragma unroll
        for (int j = 0; j < 2; j++) { acc_h[i][j] = (f32x4)0.f; acc_u[i][j] = (f32x4)0.f; }

    for (int kt = 0; kt < 16; ++kt) {
        int k0 = kt * 64;
        __syncthreads();
#pragma unroll
        for (int c = 0; c < 4; c++) async_copy16(gA[c] + k0, lA[c]);
#pragma unroll
        for (int c = 0; c < 2; c++) {
            async_copy16(gB1[c] + k0, sB1 + lBoff[c]);
            async_copy16(gB3[c] + k0, sB3 + lBoff[c]);
        }
        __syncthreads();
#pragma unroll
        for (int kk = 0; kk < 2; ++kk) {
            bf16x8 a[4], b1[2], b3[2];
#pragma unroll
            for (int i = 0; i < 4; i++) {
                int m = wm * 64 + i * 16 + l15;
                int s = (kk * 4 + quad) ^ (m & 7);
                a[i] = *(const bf16x8*)&sA[m * 64 + s * 8];
            }
#pragma unroll
            for (int j = 0; j < 2; j++) {
                int nn = wn * 32 + j * 16 + l15;
                int s = (kk * 4 + quad) ^ (nn & 7);
                b1[j] = *(const bf16x8*)&sB1[nn * 64 + s * 8];
                b3[j] = *(const bf16x8*)&sB3[nn * 64 + s * 8];
            }
#pragma unroll
            for (int i = 0; i < 4; i++)
#pragma unroll
                for (int j = 0; j < 2; j++) {
                    acc_h[i][j] = __builtin_amdgcn_mfma_f32_16x16x32_bf16(a[i], b1[j], acc_h[i][j], 0, 0, 0);
                    acc_u[i][j] = __builtin_amdgcn_mfma_f32_16x16x32_bf16(a[i], b3[j], acc_u[i][j], 0, 0, 0);
                }
        }
    }
    // epilogue: silu(h)*u -> LDS (stride 72) -> vectorized global stores
    __syncthreads();
#pragma unroll
    for (int i = 0; i < 4; i++)
#pragma unroll
        for (int j = 0; j < 2; j++)
#pragma unroll
            for (int r = 0; r < 4; r++) {
                int row = wm * 64 + i * 16 + quad * 4 + r;
                int col = wn * 32 + j * 16 + l15;
                float h = acc_h[i][j][r], u = acc_u[i][j][r];
                smem[row * 72 + col] = f2bf(h * u / (1.0f + __expf(-h)));
            }
    __syncthreads();
    int rt = tid >> 1, half = tid & 1;
    if (rt < rowsv) {
        u16* dp = Abuf + (size_t)(row0 + rt) * FDIM + bn * 64 + half * 32;
        const u16* sp = &smem[rt * 72 + half * 32];
#pragma unroll
        for (int q = 0; q < 4; q++)
            *(uint4*)(dp + q * 8) = *(const uint4*)(sp + q * 8);
    }
}

// ===================== GEMM2 + combine: out[tok] += w * (Abuf @ W2t)  (fp32 atomics) =====================
__launch_bounds__(256, 3)
__global__ void k_gemm2(const u16* __restrict__ Abuf, const u16* __restrict__ w2t,
                        const int* __restrict__ pair_token, const float* __restrict__ pair_weight,
                        const int* __restrict__ sched, float* __restrict__ outf) {
    __shared__ __align__(16) u16 smem[12288];     // 24 KB
    u16* sA = smem;                               // 128x64
    u16* sB = smem + 8192;                        // 64x64

    int bn = blockIdx.x;
    int bm = blockIdx.y;
    int total = sched[3 * MAXMT];
    if (bm >= total) return;
    int e = sched[bm];
    int row0 = sched[MAXMT + bm];
    int rowsv = sched[2 * MAXMT + bm];

    int tid = threadIdx.x;
    int wave = tid >> 6, lane = tid & 63;
    int wm = wave & 1, wn = wave >> 1;
    int quad = lane >> 4, l15 = lane & 15;
    int lsub = lane >> 3, slot = lane & 7;

    const u16* gA[4]; u16* lA[4];
#pragma unroll
    for (int c = 0; c < 4; c++) {
        int row = c * 32 + wave * 8 + lsub;
        int cr = row < rowsv ? row : 0;
        int gch = slot ^ (row & 7);
        gA[c] = Abuf + (size_t)(row0 + cr) * FDIM + gch * 8;
        lA[c] = sA + c * 2048 + wave * 512;
    }
    const u16* gB[2]; u16* lB[2];
#pragma unroll
    for (int c = 0; c < 2; c++) {
        int row = c * 32 + wave * 8 + lsub;
        int gch = slot ^ (row & 7);
        int dcol = bn * 64 + row;
        gB[c] = w2t + ((size_t)e * 1024 + dcol) * 1024 + gch * 8;
        lB[c] = sB + c * 2048 + wave * 512;
    }

    f32x4 acc[4][2];
#pragma unroll
    for (int i = 0; i < 4; i++)
#pragma unroll
        for (int j = 0; j < 2; j++) acc[i][j] = (f32x4)0.f;

    for (int kt = 0; kt < 16; ++kt) {
        int k0 = kt * 64;
        __syncthreads();
#pragma unroll
        for (int c = 0; c < 4; c++) async_copy16(gA[c] + k0, lA[c]);
#pragma unroll
        for (int c = 0; c < 2; c++) async_copy16(gB[c] + k0, lB[c]);
        __syncthreads();
#pragma unroll
        for (int kk = 0; kk < 2; ++kk) {
            bf16x8 a[4], b[2];
#pragma unroll
            for (int i = 0; i < 4; i++) {
                int m = wm * 64 + i * 16 + l15;
                int s = (kk * 4 + quad) ^ (m & 7);
                a[i] = *(const bf16x8*)&sA[m * 64 + s * 8];
            }
#pragma unroll
            for (int j = 0; j < 2; j++) {
                int nn = wn * 32 + j * 16 + l15;
                int s = (kk * 4 + quad) ^ (nn & 7);
                b[j] = *(const bf16x8*)&sB[nn * 64 + s * 8];
            }
#pragma unroll
            for (int i = 0; i < 4; i++)
#pragma unroll
                for (int j = 0; j < 2; j++)
                    acc[i][j] = __builtin_amdgcn_mfma_f32_16x16x32_bf16(a[i], b[j], acc[i][j], 0, 0, 0);
        }
    }
    // epilogue: scaled fp32 atomic adds straight into out (out zeroed by memsetAsync)
#pragma unroll
    for (int i = 0; i < 4; i++)
#pragma unroll
        for (int r = 0; r < 4; r++) {
            int lr = wm * 64 + i * 16 + quad * 4 + r;
            if (lr < rowsv) {
                int p = row0 + lr;
                int tok = pair_token[p];
                float w = pair_weight[p];
                float* op = outf + (size_t)tok * DDIM + bn * 64 + wn * 32 + l15;
#pragma unroll
                for (int j = 0; j < 2; j++)
                    atomicAdd(op + j * 16, w * acc[i][j][r]);
            }
        }
}

extern "C" void kernel_launch(void* const* d_in, const int* in_sizes, int n_in,
                              void* d_out, int out_size, void* d_ws, size_t ws_size,
                              hipStream_t stream) {
    const void* x  = d_in[0];
    const void* wg = d_in[1];
    const void* w1 = d_in[2];
    const void* w3 = d_in[3];
    const void* w2 = d_in[4];

    u16* wt   = (u16*)d_ws;                  // 48 MB: w1t(8 mats) | w3t | w2t
    u16* w1t  = wt;
    u16* w3t  = wt + (size_t)8 * 1048576;
    u16* w2t  = wt + (size_t)16 * 1048576;
    u16* Abuf = wt + (size_t)24 * 1048576;   // 8 MB
    u16* xb   = Abuf + (size_t)4096 * 1024;  // 4 MB
    int*   te   = (int*)(xb + (size_t)N_TOK * DDIM);
    float* tw   = (float*)(te + 2 * N_TOK);
    int*   ptok = (int*)(tw + 2 * N_TOK);
    float* pwt  = (float*)(ptok + 2 * N_TOK);
    int*   sched = (int*)(pwt + 2 * N_TOK);

    // zero the token-output region (fp32, confirmed); logits region fully overwritten by gating
    hipMemsetAsync(d_out, 0, (size_t)N_TOK * DDIM * sizeof(float), stream);
    k_mega<<<dim3(16, 16, 26), 256, 0, stream>>>(x, wg, w1, w3, w2, wt, xb, d_out, te, tw);
    k_sched<<<1, 256, 0, stream>>>(te, tw, ptok, pwt, sched);
    k_gemm13<<<dim3(16, MAXMT), 256, 0, stream>>>(xb, w1t, w3t, ptok, sched, Abuf);
    k_gemm2<<<dim3(16, MAXMT), 256, 0, stream>>>(Abuf, w2t, ptok, pwt, sched, (float*)d_out);
}

// Round 8
// 214.454 us; speedup vs baseline: 1.0072x; 1.0072x over previous
//
#include <hip/hip_runtime.h>
#include <stdint.h>

typedef unsigned short u16;
typedef __attribute__((ext_vector_type(8))) __bf16 bf16x8;
typedef __attribute__((ext_vector_type(4))) float f32x4;

#define MAXMT 40
#define N_TOK 2048
#define DDIM 1024
#define FDIM 1024

#define DEV static __device__ __forceinline__

DEV float bf2f(u16 u) {
    union { uint32_t i; float f; } v;
    v.i = ((uint32_t)u) << 16;
    return v.f;
}
DEV u16 f2bf(float f) {
    union { float f; uint32_t i; } v;
    v.f = f;
    uint32_t x = v.i;
    return (u16)((x + 0x7fffu + ((x >> 16) & 1u)) >> 16);  // RNE
}

// async global->LDS, 16B per lane; lds base wave-uniform, HW writes lane i at base+16*i
DEV void async_copy16(const u16* gsrc, u16* ldst) {
    __builtin_amdgcn_global_load_lds(
        (const __attribute__((address_space(1))) void*)(uintptr_t)gsrc,
        (__attribute__((address_space(3))) void*)(uint32_t)(uintptr_t)ldst,
        16, 0, 0);
}

// per-block dtype sniff: sample first 256 u16; fp32-reinterpreted data ~36% wild exponents.
DEV int sniff_fp(const void* p, int tid, int* scnt) {
    if (tid == 0) *scnt = 0;
    __syncthreads();
    u16 u = ((const u16*)p)[tid & 255];
    int e = (u >> 7) & 0xff;
    if (e != 0 && (e < 90 || e > 160)) atomicAdd(scnt, 1);
    __syncthreads();
    return *scnt > 64;
}

// ===================== mega =====================
// z in [0,24): weight transposes, 256x64 source tiles (grid x=16 col-tiles, y=4 row-tiles)
// z in [24,32): gating/normx (64 blocks per plane, 4 tokens per block)
// z in [32,36): zero d_out token region (replaces hipMemsetAsync)
__launch_bounds__(256, 4)
__global__ void k_mega(const void* __restrict__ x, const void* __restrict__ wg,
                       const void* __restrict__ w1, const void* __restrict__ w3,
                       const void* __restrict__ w2, u16* __restrict__ wt,
                       u16* __restrict__ xb, void* __restrict__ out_base,
                       int* __restrict__ te, float* __restrict__ tw) {
    __shared__ int scnt;
    __shared__ __align__(16) u16 s[256 * 66];    // 33792 B, stride 66 (odd dword stride)
    int z = blockIdx.z, tid = threadIdx.x;

    if (z < 24) {
        // ---- transpose plane: which tensor = z/8, local mat = z%8 ----
        int which = z >> 3, mat = z & 7;
        const void* src0 = which == 0 ? w1 : (which == 1 ? w3 : w2);
        int fp = sniff_fp(src0, tid, &scnt);
        u16* dst = wt + (size_t)z * 1048576;
        int r0 = blockIdx.y * 256, c0 = blockIdx.x * 64;
        int rsub = tid >> 2, seg = tid & 3;

        union { u16 v[16]; uint32_t w32[8]; uint4 q4[2]; } buf[4];
        if (fp) {
            const float* sp = (const float*)src0 + (size_t)mat * 1048576;
            float4 ld[16];
#pragma unroll
            for (int it = 0; it < 4; ++it) {
                int row = it * 64 + rsub;
                const float4* p = (const float4*)(sp + (size_t)(r0 + row) * 1024 + c0 + seg * 16);
#pragma unroll
                for (int q = 0; q < 4; ++q) ld[it * 4 + q] = p[q];
            }
#pragma unroll
            for (int it = 0; it < 4; ++it)
#pragma unroll
                for (int q = 0; q < 4; ++q) {
                    float4 f = ld[it * 4 + q];
                    buf[it].v[q * 4 + 0] = f2bf(f.x); buf[it].v[q * 4 + 1] = f2bf(f.y);
                    buf[it].v[q * 4 + 2] = f2bf(f.z); buf[it].v[q * 4 + 3] = f2bf(f.w);
                }
        } else {
            const u16* sp = (const u16*)src0 + (size_t)mat * 1048576;
#pragma unroll
            for (int it = 0; it < 4; ++it) {
                int row = it * 64 + rsub;
                const uint4* p = (const uint4*)(sp + (size_t)(r0 + row) * 1024 + c0 + seg * 16);
                buf[it].q4[0] = p[0];
                buf[it].q4[1] = p[1];
            }
        }
        // LDS stores: b32, 2-way banked (free)
        uint32_t* sd = (uint32_t*)s;
#pragma unroll
        for (int it = 0; it < 4; ++it) {
            int row = it * 64 + rsub;
            int base = row * 33 + seg * 8;
#pragma unroll
            for (int q = 0; q < 8; ++q) sd[base + q] = buf[it].w32[q];
        }
        __syncthreads();
        // phase 2: cluster-of-4 lanes share dst row d -> 128 B contiguous writes
        int d = tid >> 2, sub = tid & 3;
#pragma unroll
        for (int it = 0; it < 4; ++it) {
            int j = it * 4 + sub;
            u16 tmp[16];
#pragma unroll
            for (int i = 0; i < 16; ++i) tmp[i] = s[(j * 16 + i) * 66 + d];
            u16* dp = dst + (size_t)(c0 + d) * 1024 + r0 + j * 16;
            *(uint4*)dp = *(const uint4*)&tmp[0];
            *(uint4*)(dp + 8) = *(const uint4*)&tmp[8];
        }
    } else if (z < 32) {
        // ---- gating plane: 512 blocks total, 4 tokens each; also emits xb (bf16 x) ----
        int fp = sniff_fp(x, tid, &scnt);
        int gi = (z - 24) * 64 + blockIdx.y * 16 + blockIdx.x;
        int wave = tid >> 6, lane = tid & 63;
        int n = gi * 4 + wave;
        float acc[8];
#pragma unroll
        for (int e = 0; e < 8; e++) acc[e] = 0.f;
        if (fp) {
            const float* xp = (const float*)x + (size_t)n * DDIM;
            const float* wp = (const float*)wg;
            for (int it = 0; it < 16; ++it) {
                int d = it * 64 + lane;
                float xv = xp[d];
                xb[(size_t)n * DDIM + d] = f2bf(xv);
#pragma unroll
                for (int e = 0; e < 8; e++) acc[e] += xv * wp[e * DDIM + d];
            }
        } else {
            const u16* xp = (const u16*)x + (size_t)n * DDIM;
            const u16* wp = (const u16*)wg;
            for (int it = 0; it < 16; ++it) {
                int d = it * 64 + lane;
                u16 raw = xp[d];
                xb[(size_t)n * DDIM + d] = raw;
                float xv = bf2f(raw);
#pragma unroll
                for (int e = 0; e < 8; e++) acc[e] += xv * bf2f(wp[e * DDIM + d]);
            }
        }
#pragma unroll
        for (int e = 0; e < 8; e++) {
            for (int off = 32; off; off >>= 1) acc[e] += __shfl_xor(acc[e], off);
        }
        if (lane < 8) {
            if (fp) ((float*)out_base + (size_t)N_TOK * DDIM)[n * 8 + lane] = acc[lane];
            else    ((u16*)out_base + (size_t)N_TOK * DDIM)[n * 8 + lane] = f2bf(acc[lane]);
        }
        if (lane == 0) {
            int e0 = 0; float b0 = acc[0];
            for (int e = 1; e < 8; e++) if (acc[e] > b0) { b0 = acc[e]; e0 = e; }
            int e1 = -1; float b1 = -1e30f;
            for (int e = 0; e < 8; e++) if (e != e0 && acc[e] > b1) { b1 = acc[e]; e1 = e; }
            float m = fmaxf(b0, b1);
            float x0 = __expf(b0 - m), x1 = __expf(b1 - m);
            float sden = x0 + x1;
            te[n * 2] = e0; te[n * 2 + 1] = e1;
            tw[n * 2] = x0 / sden; tw[n * 2 + 1] = x1 / sden;
        }
    } else {
        // ---- zero plane: clear token-output region of d_out (fp32) ----
        float4* op = (float4*)out_base + ((size_t)(z - 32) * 64 + blockIdx.y * 16 + blockIdx.x) * 2048;
        float4 zz = { 0.f, 0.f, 0.f, 0.f };
#pragma unroll
        for (int q = 0; q < 8; ++q) op[q * 256 + tid] = zz;
    }
}

// ---------------- scheduling ----------------
__global__ void k_sched(const int* __restrict__ te, const float* __restrict__ tw,
                        int* __restrict__ pair_token, float* __restrict__ pair_weight,
                        int* __restrict__ sched) {
    __shared__ int cnt[8], cur[8];
    int t = threadIdx.x;
    if (t < 8) cnt[t] = 0;
    __syncthreads();
    for (int n = t; n < N_TOK; n += 256) {
        atomicAdd(&cnt[te[2 * n]], 1);
        atomicAdd(&cnt[te[2 * n + 1]], 1);
    }
    __syncthreads();
    if (t == 0) {
        int o = 0, mt = 0;
        for (int e = 0; e < 8; e++) {
            cur[e] = o;
            int c = cnt[e];
            for (int m0 = 0; m0 < c; m0 += 128) {
                sched[mt] = e;
                sched[MAXMT + mt] = o + m0;
                sched[2 * MAXMT + mt] = (c - m0 < 128) ? (c - m0) : 128;
                mt++;
            }
            o += c;
        }
        sched[3 * MAXMT] = mt;
        for (int i = mt; i < MAXMT; i++) { sched[i] = 0; sched[MAXMT + i] = 0; sched[2 * MAXMT + i] = 0; }
    }
    __syncthreads();
    for (int n = t; n < N_TOK; n += 256) {
#pragma unroll
        for (int s = 0; s < 2; s++) {
            int e = te[2 * n + s];
            int p = atomicAdd(&cur[e], 1);
            pair_token[p] = n;
            pair_weight[p] = tw[2 * n + s];
        }
    }
}

// ===================== fused SwiGLU GEMM: Abuf = silu(X@W1) * (X@W3) =====================
__launch_bounds__(256, 3)
__global__ void k_gemm13(const u16* __restrict__ xb, const u16* __restrict__ w1t,
                         const u16* __restrict__ w3t, const int* __restrict__ pair_token,
                         const int* __restrict__ sched, u16* __restrict__ Abuf) {
    __shared__ __align__(16) u16 smem[16384];     // 32 KB
    u16* sA  = smem;                              // 128x64
    u16* sB1 = smem + 8192;                       // 64x64
    u16* sB3 = smem + 12288;                      // 64x64

    int bn = blockIdx.x;          // 16 tiles of 64 cols
    int bm = blockIdx.y;
    int total = sched[3 * MAXMT];
    if (bm >= total) return;
    int e = sched[bm];
    int row0 = sched[MAXMT + bm];
    int rowsv = sched[2 * MAXMT + bm];

    int tid = threadIdx.x;
    int wave = tid >> 6, lane = tid & 63;
    int wm = wave & 1, wn = wave >> 1;            // wave: 64m x 32n
    int quad = lane >> 4, l15 = lane & 15;
    int lsub = lane >> 3, slot = lane & 7;

    const u16* gA[4]; u16* lA[4];
#pragma unroll
    for (int c = 0; c < 4; c++) {
        int row = c * 32 + wave * 8 + lsub;       // 0..127
        int cr = row < rowsv ? row : 0;
        int tok = pair_token[row0 + cr];
        int gch = slot ^ (row & 7);
        gA[c] = xb + (size_t)tok * DDIM + gch * 8;
        lA[c] = sA + c * 2048 + wave * 512;
    }
    const u16* gB1[2]; const u16* gB3[2]; int lBoff[2];
#pragma unroll
    for (int c = 0; c < 2; c++) {
        int row = c * 32 + wave * 8 + lsub;       // 0..63
        int gch = slot ^ (row & 7);
        int fcol = bn * 64 + row;
        gB1[c] = w1t + ((size_t)e * 1024 + fcol) * 1024 + gch * 8;
        gB3[c] = w3t + ((size_t)e * 1024 + fcol) * 1024 + gch * 8;
        lBoff[c] = c * 2048 + wave * 512;
    }

    f32x4 acc_h[4][2], acc_u[4][2];
#pragma unroll
    for (int i = 0; i < 4; i++)
#pragma unroll
        for (int j = 0; j < 2; j++) { acc_h[i][j] = (f32x4)0.f; acc_u[i][j] = (f32x4)0.f; }

    for (int kt = 0; kt < 16; ++kt) {
        int k0 = kt * 64;
        __syncthreads();
#pragma unroll
        for (int c = 0; c < 4; c++) async_copy16(gA[c] + k0, lA[c]);
#pragma unroll
        for (int c = 0; c < 2; c++) {
            async_copy16(gB1[c] + k0, sB1 + lBoff[c]);
            async_copy16(gB3[c] + k0, sB3 + lBoff[c]);
        }
        __syncthreads();
#pragma unroll
        for (int kk = 0; kk < 2; ++kk) {
            bf16x8 a[4], b1[2], b3[2];
#pragma unroll
            for (int i = 0; i < 4; i++) {
                int m = wm * 64 + i * 16 + l15;
                int s = (kk * 4 + quad) ^ (m & 7);
                a[i] = *(const bf16x8*)&sA[m * 64 + s * 8];
            }
#pragma unroll
            for (int j = 0; j < 2; j++) {
                int nn = wn * 32 + j * 16 + l15;
                int s = (kk * 4 + quad) ^ (nn & 7);
                b1[j] = *(const bf16x8*)&sB1[nn * 64 + s * 8];
                b3[j] = *(const bf16x8*)&sB3[nn * 64 + s * 8];
            }
#pragma unroll
            for (int i = 0; i < 4; i++)
#pragma unroll
                for (int j = 0; j < 2; j++) {
                    acc_h[i][j] = __builtin_amdgcn_mfma_f32_16x16x32_bf16(a[i], b1[j], acc_h[i][j], 0, 0, 0);
                    acc_u[i][j] = __builtin_amdgcn_mfma_f32_16x16x32_bf16(a[i], b3[j], acc_u[i][j], 0, 0, 0);
                }
        }
    }
    // epilogue: silu(h)*u -> LDS (stride 72) -> vectorized global stores
    __syncthreads();
#pragma unroll
    for (int i = 0; i < 4; i++)
#pragma unroll
        for (int j = 0; j < 2; j++)
#pragma unroll
            for (int r = 0; r < 4; r++) {
                int row = wm * 64 + i * 16 + quad * 4 + r;
                int col = wn * 32 + j * 16 + l15;
                float h = acc_h[i][j][r], u = acc_u[i][j][r];
                smem[row * 72 + col] = f2bf(h * u / (1.0f + __expf(-h)));
            }
    __syncthreads();
    int rt = tid >> 1, half = tid & 1;
    if (rt < rowsv) {
        u16* dp = Abuf + (size_t)(row0 + rt) * FDIM + bn * 64 + half * 32;
        const u16* sp = &smem[rt * 72 + half * 32];
#pragma unroll
        for (int q = 0; q < 4; q++)
            *(uint4*)(dp + q * 8) = *(const uint4*)(sp + q * 8);
    }
}

// ===================== GEMM2 + combine: out[tok] += w * (Abuf @ W2t)  (fp32 atomics) =====================
__launch_bounds__(256, 3)
__global__ void k_gemm2(const u16* __restrict__ Abuf, const u16* __restrict__ w2t,
                        const int* __restrict__ pair_token, const float* __restrict__ pair_weight,
                        const int* __restrict__ sched, float* __restrict__ outf) {
    __shared__ __align__(16) u16 smem[12288];     // 24 KB
    u16* sA = smem;                               // 128x64
    u16* sB = smem + 8192;                        // 64x64

    int bn = blockIdx.x;
    int bm = blockIdx.y;
    int total = sched[3 * MAXMT];
    if (bm >= total) return;
    int e = sched[bm];
    int row0 = sched[MAXMT + bm];
    int rowsv = sched[2 * MAXMT + bm];

    int tid = threadIdx.x;
    int wave = tid >> 6, lane = tid & 63;
    int wm = wave & 1, wn = wave >> 1;
    int quad = lane >> 4, l15 = lane & 15;
    int lsub = lane >> 3, slot = lane & 7;

    const u16* gA[4]; u16* lA[4];
#pragma unroll
    for (int c = 0; c < 4; c++) {
        int row = c * 32 + wave * 8 + lsub;
        int cr = row < rowsv ? row : 0;
        int gch = slot ^ (row & 7);
        gA[c] = Abuf + (size_t)(row0 + cr) * FDIM + gch * 8;
        lA[c] = sA + c * 2048 + wave * 512;
    }
    const u16* gB[2]; u16* lB[2];
#pragma unroll
    for (int c = 0; c < 2; c++) {
        int row = c * 32 + wave * 8 + lsub;
        int gch = slot ^ (row & 7);
        int dcol = bn * 64 + row;
        gB[c] = w2t + ((size_t)e * 1024 + dcol) * 1024 + gch * 8;
        lB[c] = sB + c * 2048 + wave * 512;
    }

    f32x4 acc[4][2];
#pragma unroll
    for (int i = 0; i < 4; i++)
#pragma unroll
        for (int j = 0; j < 2; j++) acc[i][j] = (f32x4)0.f;

    for (int kt = 0; kt < 16; ++kt) {
        int k0 = kt * 64;
        __syncthreads();
#pragma unroll
        for (int c = 0; c < 4; c++) async_copy16(gA[c] + k0, lA[c]);
#pragma unroll
        for (int c = 0; c < 2; c++) async_copy16(gB[c] + k0, lB[c]);
        __syncthreads();
#pragma unroll
        for (int kk = 0; kk < 2; ++kk) {
            bf16x8 a[4], b[2];
#pragma unroll
            for (int i = 0; i < 4; i++) {
                int m = wm * 64 + i * 16 + l15;
                int s = (kk * 4 + quad) ^ (m & 7);
                a[i] = *(const bf16x8*)&sA[m * 64 + s * 8];
            }
#pragma unroll
            for (int j = 0; j < 2; j++) {
                int nn = wn * 32 + j * 16 + l15;
                int s = (kk * 4 + quad) ^ (nn & 7);
                b[j] = *(const bf16x8*)&sB[nn * 64 + s * 8];
            }
#pragma unroll
            for (int i = 0; i < 4; i++)
#pragma unroll
                for (int j = 0; j < 2; j++)
                    acc[i][j] = __builtin_amdgcn_mfma_f32_16x16x32_bf16(a[i], b[j], acc[i][j], 0, 0, 0);
        }
    }
    // epilogue: scaled fp32 atomic adds straight into out (zeroed by k_mega zero-planes)
#pragma unroll
    for (int i = 0; i < 4; i++)
#pragma unroll
        for (int r = 0; r < 4; r++) {
            int lr = wm * 64 + i * 16 + quad * 4 + r;
            if (lr < rowsv) {
                int p = row0 + lr;
                int tok = pair_token[p];
                float w = pair_weight[p];
                float* op = outf + (size_t)tok * DDIM + bn * 64 + wn * 32 + l15;
#pragma unroll
                for (int j = 0; j < 2; j++)
                    atomicAdd(op + j * 16, w * acc[i][j][r]);
            }
        }
}

extern "C" void kernel_launch(void* const* d_in, const int* in_sizes, int n_in,
                              void* d_out, int out_size, void* d_ws, size_t ws_size,
                              hipStream_t stream) {
    const void* x  = d_in[0];
    const void* wg = d_in[1];
    const void* w1 = d_in[2];
    const void* w3 = d_in[3];
    const void* w2 = d_in[4];

    u16* wt   = (u16*)d_ws;                  // 48 MB: w1t(8 mats) | w3t | w2t
    u16* w1t  = wt;
    u16* w3t  = wt + (size_t)8 * 1048576;
    u16* w2t  = wt + (size_t)16 * 1048576;
    u16* Abuf = wt + (size_t)24 * 1048576;   // 8 MB
    u16* xb   = Abuf + (size_t)4096 * 1024;  // 4 MB
    int*   te   = (int*)(xb + (size_t)N_TOK * DDIM);
    float* tw   = (float*)(te + 2 * N_TOK);
    int*   ptok = (int*)(tw + 2 * N_TOK);
    float* pwt  = (float*)(ptok + 2 * N_TOK);
    int*   sched = (int*)(pwt + 2 * N_TOK);

    k_mega<<<dim3(16, 4, 36), 256, 0, stream>>>(x, wg, w1, w3, w2, wt, xb, d_out, te, tw);
    k_sched<<<1, 256, 0, stream>>>(te, tw, ptok, pwt, sched);
    k_gemm13<<<dim3(16, MAXMT), 256, 0, stream>>>(xb, w1t, w3t, ptok, sched, Abuf);
    k_gemm2<<<dim3(16, MAXMT), 256, 0, stream>>>(Abuf, w2t, ptok, pwt, sched, (float*)d_out);
}